// Round 12
// baseline (73.540 us; speedup 1.0000x reference)
//
#include <hip/hip_runtime.h>
#include <hip/hip_bf16.h>

// Disable FMA contraction globally: the coordinate transform
// (p+1)*scale-0.5 must round exactly like numpy float32, or floor()
// can flip a cell index and change which octree keys we look up.
#pragma clang fp contract(off)

// Keyspace <= 2^26 (depth=8, B=4). One block per 64 key values.
// Hot structure split by access probability:
//   bits8[b] : u64 presence bits  (8 MB)  -- touched by EVERY corner (97% stop here)
//   srt[b]   : u32 start | dup<<31 (4 MB) -- touched only by hit corners (~3%)
// Both morton-block-indexed (b = key >> 6).
#define NBLKP (1 << 20)
#define K_BITS 18  // fallback bucket bits (1 MB table)

typedef float f32x4 __attribute__((ext_vector_type(4)));

// Morton bit-spread of the low 8 bits of v: bit d -> bit 3d.
// Bit-exact with the reference loop incl. negative / overflowed coords
// (two's complement low bits == the reference's per-bit (v>>d)&1).
__device__ __forceinline__ unsigned morton_spread(unsigned v) {
  v = (v | (v << 16)) & 0x030000FFu;
  v = (v | (v << 8)) & 0x0300F00Fu;
  v = (v | (v << 4)) & 0x030C30C3u;
  v = (v | (v << 2)) & 0x09249249u;
  return v;
}

__device__ __forceinline__ int morton_key(float xi, float yi, float zi,
                                          int gx, int gy, int gz, int b,
                                          int depth, unsigned cmask) {
  unsigned ux = ((unsigned)((int)xi + gx)) & cmask;
  unsigned uy = ((unsigned)((int)yi + gy)) & cmask;
  unsigned uz = ((unsigned)((int)zi + gz)) & cmask;
  return (int)((morton_spread(ux) << 2) | (morton_spread(uy) << 1) |
               morton_spread(uz)) | (b << (3 * depth));
}

// ---------------------------------------------------------------------------
// P1: prefill start-tab with H (buckets past the last key = lower_bound end)
// ---------------------------------------------------------------------------
__global__ __launch_bounds__(256) void octi_fill_tab(
    int* __restrict__ tab, int n, int H) {
  int j = blockIdx.x * 256 + threadIdx.x;
  if (j < n) tab[j] = H;
}

// ---------------------------------------------------------------------------
// P2: tab[b] = lower_bound(keys, b<<6). Thread m owns buckets
// (keys[m-1]>>6, keys[m]>>6]  (thread 0: [0, keys[0]>>6]). Disjoint, no atomics.
// ---------------------------------------------------------------------------
__global__ __launch_bounds__(256) void octi_scatter6(
    const int* __restrict__ keys, int H, int* __restrict__ tab) {
  int m = blockIdx.x * 256 + threadIdx.x;
  if (m >= H) return;
  int bc = (int)(((unsigned)keys[m]) >> 6);
  int bp = (m == 0) ? -1 : (int)(((unsigned)keys[m - 1]) >> 6);
  for (int j = bp + 1; j <= bc; ++j) tab[j] = m;
}

// ---------------------------------------------------------------------------
// P3: pack per block: bits8[b] = presence bits; srt[b] = start | dup<<31.
// dup=1 iff the block holds a duplicated key (then the main kernel must
// scan keys for the exact searchsorted-left row). Empty blocks: bits=0.
// ---------------------------------------------------------------------------
__global__ __launch_bounds__(256) void octi_pack(
    const int* __restrict__ keys, const int* __restrict__ tab,
    unsigned long long* __restrict__ bits8, unsigned* __restrict__ srt) {
  int b = blockIdx.x * 256 + threadIdx.x;
  if (b >= NBLKP) return;
  int s = tab[b], e = tab[b + 1];
  unsigned long long bits = 0ull;
  for (int m = s; m < e; ++m)
    bits |= 1ull << (((unsigned)keys[m]) & 63u);
  unsigned dup = ((e - s) != __popcll(bits)) ? 1u : 0u;
  bits8[b] = bits;
  srt[b] = (unsigned)s | (dup << 31);
}

// ---------------------------------------------------------------------------
// Main interpolation, C == 32 fast path.  8 lanes per group; each group
// handles TWO independent points (i, i+half).  lane = corner index (lookup)
// and channel-quad (gather/write, float4).  One 8B random load resolves
// presence; hit corners (~3%) read srt (+ rare dup scan of keys).
// Plain (L2 write-combined) float4 stores for the 134 MB out stream.
// ---------------------------------------------------------------------------
__global__ __launch_bounds__(256) void octi_interp32(
    const float* __restrict__ data, const float* __restrict__ pts,
    const int* __restrict__ keys, const int* __restrict__ depth_ptr,
    const unsigned long long* __restrict__ bits8,
    const unsigned* __restrict__ srt, float* __restrict__ out,
    int N, int half) {
  int t = blockIdx.x * 256 + threadIdx.x;
  int g = t >> 3;
  if (g >= half) return;
  int l = t & 7;
  int i0 = g;
  int i1 = g + half;
  bool has1 = i1 < N;

  int depth = *depth_ptr;
  float scale = (float)(1 << (depth - 1));
  unsigned cmask = (1u << depth) - 1u;
  int gx = (l >> 2) & 1, gy = (l >> 1) & 1, gz = l & 1;

  // ---- phase A: coords + keys for both points ----
  float4 p0 = reinterpret_cast<const float4*>(pts)[i0];
  float4 p1 = reinterpret_cast<const float4*>(pts)[has1 ? i1 : i0];

  // exact numpy-f32 sequence: (p + 1.0f) * scale - 0.5f  (no contraction)
  float xf0 = (p0.x + 1.0f) * scale - 0.5f;
  float yf0 = (p0.y + 1.0f) * scale - 0.5f;
  float zf0 = (p0.z + 1.0f) * scale - 0.5f;
  float xi0 = floorf(xf0), yi0 = floorf(yf0), zi0 = floorf(zf0);
  float fx0 = xf0 - xi0, fy0 = yf0 - yi0, fz0 = zf0 - zi0;
  int key0 = morton_key(xi0, yi0, zi0, gx, gy, gz, (int)p0.w, depth, cmask);

  float xf1 = (p1.x + 1.0f) * scale - 0.5f;
  float yf1 = (p1.y + 1.0f) * scale - 0.5f;
  float zf1 = (p1.z + 1.0f) * scale - 0.5f;
  float xi1 = floorf(xf1), yi1 = floorf(yf1), zi1 = floorf(zf1);
  float fx1 = xf1 - xi1, fy1 = yf1 - yi1, fz1 = zf1 - zi1;
  int key1 = morton_key(xi1, yi1, zi1, gx, gy, gz, (int)p1.w, depth, cmask);

  // ---- phase B: both presence loads issued back-to-back (8B each) ----
  unsigned long long bits0 = bits8[((unsigned)key0) >> 6];
  unsigned long long bits1 = bits8[((unsigned)key1) >> 6];

  // ---- phase C: presence + row; srt only on hit, keys only on dup ----
  int bit0 = key0 & 63;
  bool present0 = (bits0 >> bit0) & 1ull;
  int pos0 = 0;
  if (present0) {
    unsigned sv = srt[((unsigned)key0) >> 6];
    pos0 = (int)(sv & 0x7FFFFFFFu) +
           (int)__popcll(bits0 & ((1ull << bit0) - 1ull));
    if (sv >> 31) {                 // duplicate-key block: exact scan
      int row = (int)(sv & 0x7FFFFFFFu);
      while (keys[row] < key0) ++row;
      pos0 = row;
    }
  }

  int bit1 = key1 & 63;
  bool present1 = has1 && ((bits1 >> bit1) & 1ull);
  int pos1 = 0;
  if (present1) {
    unsigned sv = srt[((unsigned)key1) >> 6];
    pos1 = (int)(sv & 0x7FFFFFFFu) +
           (int)__popcll(bits1 & ((1ull << bit1) - 1ull));
    if (sv >> 31) {
      int row = (int)(sv & 0x7FFFFFFFu);
      while (keys[row] < key1) ++row;
      pos1 = row;
    }
  }

  // ---- phase D: weights, ballot-driven gather, coalesced store ----
  int lane = threadIdx.x & 63;
  int base = lane & 56;

  float wx0 = (1.0f - (float)gx) - fx0;
  float wy0 = (1.0f - (float)gy) - fy0;
  float wz0 = (1.0f - (float)gz) - fz0;
  float w0 = present0 ? fabsf((wx0 * wy0) * wz0) : 0.0f;

  float wx1 = (1.0f - (float)gx) - fx1;
  float wy1 = (1.0f - (float)gy) - fy1;
  float wz1 = (1.0f - (float)gz) - fz1;
  float w1 = present1 ? fabsf((wx1 * wy1) * wz1) : 0.0f;

  unsigned long long ball0 = __ballot(w0 != 0.0f);
  unsigned long long ball1 = __ballot(w1 != 0.0f);

  {
    unsigned g8 = (unsigned)((ball0 >> base) & 0xFFull);
    float4 acc = make_float4(0.f, 0.f, 0.f, 0.f);
    float norm = 0.0f;
    while (g8) {
      int q = __ffs(g8) - 1;
      g8 &= g8 - 1;
      float wq = __shfl(w0, base + q, 64);
      int   pq = __shfl(pos0, base + q, 64);
      norm += wq;
      float4 f = reinterpret_cast<const float4*>(data)[pq * 8 + l];
      acc.x += wq * f.x;
      acc.y += wq * f.y;
      acc.z += wq * f.z;
      acc.w += wq * f.w;
    }
    float inv = 1.0f / (norm + 1e-12f);
    float4 o = make_float4(acc.x * inv, acc.y * inv, acc.z * inv, acc.w * inv);
    reinterpret_cast<float4*>(out)[i0 * 8 + l] = o;
  }
  if (has1) {
    unsigned g8 = (unsigned)((ball1 >> base) & 0xFFull);
    float4 acc = make_float4(0.f, 0.f, 0.f, 0.f);
    float norm = 0.0f;
    while (g8) {
      int q = __ffs(g8) - 1;
      g8 &= g8 - 1;
      float wq = __shfl(w1, base + q, 64);
      int   pq = __shfl(pos1, base + q, 64);
      norm += wq;
      float4 f = reinterpret_cast<const float4*>(data)[pq * 8 + l];
      acc.x += wq * f.x;
      acc.y += wq * f.y;
      acc.z += wq * f.z;
      acc.w += wq * f.w;
    }
    float inv = 1.0f / (norm + 1e-12f);
    float4 o = make_float4(acc.x * inv, acc.y * inv, acc.z * inv, acc.w * inv);
    reinterpret_cast<float4*>(out)[i1 * 8 + l] = o;
  }
}

// ---------------------------------------------------------------------------
// Fallback path (small ws or C != 32): bucketed binary search, one thread/point.
// ---------------------------------------------------------------------------
__global__ __launch_bounds__(256) void octi_scatter_k(
    const int* __restrict__ keys, int H, const int* __restrict__ depth_ptr,
    int* __restrict__ tab, int kbits) {
  int m = blockIdx.x * 256 + threadIdx.x;
  if (m >= H) return;
  int depth = *depth_ptr;
  int kb = 3 * depth + 2;
  int S = kb > kbits ? kb - kbits : 0;
  int bc = (int)(((unsigned)keys[m]) >> S);
  int bp = (m == 0) ? -1 : (int)(((unsigned)keys[m - 1]) >> S);
  for (int j = bp + 1; j <= bc; ++j) tab[j] = m;
}

__global__ __launch_bounds__(256) void octi_interp_gen(
    const float* __restrict__ data, const float* __restrict__ pts,
    const int* __restrict__ keys, const int* __restrict__ depth_ptr,
    const int* __restrict__ tab, float* __restrict__ out,
    int N, int H, int C, int kbits) {
  int i = blockIdx.x * 256 + threadIdx.x;
  if (i >= N) return;
  int depth = *depth_ptr;
  int kb = 3 * depth + 2;
  int S = kb > kbits ? kb - kbits : 0;
  float scale = (float)(1 << (depth - 1));
  unsigned cmask = (1u << depth) - 1u;
  const float4 p = reinterpret_cast<const float4*>(pts)[i];
  float xf = (p.x + 1.0f) * scale - 0.5f;
  float yf = (p.y + 1.0f) * scale - 0.5f;
  float zf = (p.z + 1.0f) * scale - 0.5f;
  float xi = floorf(xf), yi = floorf(yf), zi = floorf(zf);
  float fx = xf - xi, fy = yf - yi, fz = zf - zi;
  int b = (int)p.w;
  float wv[8]; int pv[8];
  float norm = 0.0f;
  for (int l = 0; l < 8; ++l) {
    int gx = (l >> 2) & 1, gy = (l >> 1) & 1, gz = l & 1;
    int key = morton_key(xi, yi, zi, gx, gy, gz, b, depth, cmask);
    unsigned bkt = ((unsigned)key) >> S;
    int lo = tab ? tab[bkt] : 0;
    int hi = tab ? tab[bkt + 1] : H;
    bool present = false; int posc = 0;
    if (lo < hi) {
      int hi0 = hi;
      while (lo < hi) { int mid = (lo + hi) >> 1; if (keys[mid] < key) lo = mid + 1; else hi = mid; }
      present = (lo < hi0) && (keys[lo] == key);
      posc = lo;
    }
    float wx = (1.0f - (float)gx) - fx;
    float wy = (1.0f - (float)gy) - fy;
    float wz = (1.0f - (float)gz) - fz;
    float w = present ? fabsf((wx * wy) * wz) : 0.0f;
    wv[l] = w; pv[l] = posc; norm += w;
  }
  float dnm = norm + 1e-12f;
  for (int c = 0; c < C; ++c) {
    float acc = 0.0f;
    for (int q = 0; q < 8; ++q)
      if (wv[q] != 0.0f) acc += wv[q] * data[(long long)pv[q] * C + c];
    out[(long long)i * C + c] = acc / dnm;
  }
}

extern "C" void kernel_launch(void* const* d_in, const int* in_sizes, int n_in,
                              void* d_out, int out_size, void* d_ws, size_t ws_size,
                              hipStream_t stream) {
  const float* data = (const float*)d_in[0];
  const float* pts  = (const float*)d_in[1];
  const int*   keys = (const int*)d_in[2];
  const int*   dep  = (const int*)d_in[3];
  float* out = (float*)d_out;

  int H = in_sizes[2];
  int N = in_sizes[1] / 4;
  int C = (H > 0) ? in_sizes[0] / H : 0;

  // workspace layout: bits8 (8 MB) + srt (4 MB) + tab (4 MB + 4)
  size_t off_bits = 0;
  size_t off_srt  = (size_t)NBLKP * 8;
  size_t off_tab  = off_srt + (size_t)NBLKP * 4;
  size_t need = off_tab + ((size_t)NBLKP + 1) * 4;

  if (C == 32 && ws_size >= need) {
    unsigned long long* bits8 = (unsigned long long*)((char*)d_ws + off_bits);
    unsigned* srt = (unsigned*)((char*)d_ws + off_srt);
    int*      tab = (int*)((char*)d_ws + off_tab);

    octi_fill_tab<<<(NBLKP + 1 + 255) / 256, 256, 0, stream>>>(tab, NBLKP + 1, H);
    octi_scatter6<<<(H + 255) / 256, 256, 0, stream>>>(keys, H, tab);
    octi_pack<<<NBLKP / 256, 256, 0, stream>>>(keys, tab, bits8, srt);

    int half = (N + 1) >> 1;
    long long tt = (long long)half * 8;
    octi_interp32<<<(int)((tt + 255) / 256), 256, 0, stream>>>(
        data, pts, keys, dep, bits8, srt, out, N, half);
  } else {
    int kbits = K_BITS;
    int NB1 = (1 << kbits) + 1;
    bool useTab = ws_size >= (size_t)NB1 * sizeof(int);
    int* tab = (int*)d_ws;
    if (useTab) {
      octi_fill_tab<<<(NB1 + 255) / 256, 256, 0, stream>>>(tab, NB1, H);
      octi_scatter_k<<<(H + 255) / 256, 256, 0, stream>>>(keys, H, dep, tab, kbits);
    }
    octi_interp_gen<<<(N + 255) / 256, 256, 0, stream>>>(
        data, pts, keys, dep, useTab ? tab : nullptr, out, N, H, C, kbits);
  }
}

// Round 13
// 64.961 us; speedup vs baseline: 1.1321x; 1.1321x over previous
//
#include <hip/hip_runtime.h>
#include <hip/hip_bf16.h>

// Disable FMA contraction globally: the coordinate transform
// (p+1)*scale-0.5 must round exactly like numpy float32, or floor()
// can flip a cell index and change which octree keys we look up.
#pragma clang fp contract(off)

// Keyspace <= 2^26 (depth=8, B=4). One block per 64 key values.
// Hot structure split by access probability:
//   bits8[b] : u64 presence bits  (8 MB)  -- touched by EVERY corner (97% stop here)
//   srt[b]   : u32 start | dup<<31 (4 MB) -- touched only by hit corners (~3%)
// Both morton-block-indexed (b = key >> 6).
#define NBLKP (1 << 20)
#define K_BITS 18  // fallback bucket bits (1 MB table)

typedef float f32x4 __attribute__((ext_vector_type(4)));

// Morton bit-spread of the low 8 bits of v: bit d -> bit 3d.
// Bit-exact with the reference loop incl. negative / overflowed coords
// (two's complement low bits == the reference's per-bit (v>>d)&1).
__device__ __forceinline__ unsigned morton_spread(unsigned v) {
  v = (v | (v << 16)) & 0x030000FFu;
  v = (v | (v << 8)) & 0x0300F00Fu;
  v = (v | (v << 4)) & 0x030C30C3u;
  v = (v | (v << 2)) & 0x09249249u;
  return v;
}

__device__ __forceinline__ int morton_key(float xi, float yi, float zi,
                                          int gx, int gy, int gz, int b,
                                          int depth, unsigned cmask) {
  unsigned ux = ((unsigned)((int)xi + gx)) & cmask;
  unsigned uy = ((unsigned)((int)yi + gy)) & cmask;
  unsigned uz = ((unsigned)((int)zi + gz)) & cmask;
  return (int)((morton_spread(ux) << 2) | (morton_spread(uy) << 1) |
               morton_spread(uz)) | (b << (3 * depth));
}

// ---------------------------------------------------------------------------
// P1: tab[b] = lower_bound(keys, b<<6), COMPLETE (no prefill needed):
//   thread 0    fills [0, bc_0]
//   thread m    fills (bc_{m-1}, bc_m]
//   thread H-1  additionally fills (bc_{H-1}, NBLKP] with H
// Disjoint ranges -> no races, no atomics. For uniform keys the head/tail
// runs are tiny (~NBLKP/H per thread on average).
// ---------------------------------------------------------------------------
__global__ __launch_bounds__(256) void octi_scatter6(
    const int* __restrict__ keys, int H, int* __restrict__ tab) {
  int m = blockIdx.x * 256 + threadIdx.x;
  if (m >= H) return;
  int bc = (int)(((unsigned)keys[m]) >> 6);
  int bp = (m == 0) ? -1 : (int)(((unsigned)keys[m - 1]) >> 6);
  for (int j = bp + 1; j <= bc; ++j) tab[j] = m;
  if (m == H - 1) {
    for (int j = bc + 1; j <= NBLKP; ++j) tab[j] = H;
  }
}

// ---------------------------------------------------------------------------
// P2: pack per block: bits8[b] = presence bits; srt[b] = start | dup<<31.
// dup=1 iff the block holds a duplicated key (then the main kernel must
// scan keys for the exact searchsorted-left row). Empty blocks: bits=0.
// ---------------------------------------------------------------------------
__global__ __launch_bounds__(256) void octi_pack(
    const int* __restrict__ keys, const int* __restrict__ tab,
    unsigned long long* __restrict__ bits8, unsigned* __restrict__ srt) {
  int b = blockIdx.x * 256 + threadIdx.x;
  if (b >= NBLKP) return;
  int s = tab[b], e = tab[b + 1];
  unsigned long long bits = 0ull;
  for (int m = s; m < e; ++m)
    bits |= 1ull << (((unsigned)keys[m]) & 63u);
  unsigned dup = ((e - s) != __popcll(bits)) ? 1u : 0u;
  bits8[b] = bits;
  srt[b] = (unsigned)s | (dup << 31);
}

// ---------------------------------------------------------------------------
// Main interpolation, C == 32 fast path.  8 lanes per group; each group
// handles TWO independent points (i, i+half).  lane = corner index (lookup)
// and channel-quad (gather/write, float4).  One 8B random load resolves
// presence; hit corners (~3%) read srt (+ rare dup scan of keys).
// NT stores keep the 134 MB out stream from evicting bits8/srt in L2.
// ---------------------------------------------------------------------------
__global__ __launch_bounds__(256) void octi_interp32(
    const float* __restrict__ data, const float* __restrict__ pts,
    const int* __restrict__ keys, const int* __restrict__ depth_ptr,
    const unsigned long long* __restrict__ bits8,
    const unsigned* __restrict__ srt, float* __restrict__ out,
    int N, int half) {
  int t = blockIdx.x * 256 + threadIdx.x;
  int g = t >> 3;
  if (g >= half) return;
  int l = t & 7;
  int i0 = g;
  int i1 = g + half;
  bool has1 = i1 < N;

  int depth = *depth_ptr;
  float scale = (float)(1 << (depth - 1));
  unsigned cmask = (1u << depth) - 1u;
  int gx = (l >> 2) & 1, gy = (l >> 1) & 1, gz = l & 1;

  // ---- phase A: coords + keys for both points ----
  float4 p0 = reinterpret_cast<const float4*>(pts)[i0];
  float4 p1 = reinterpret_cast<const float4*>(pts)[has1 ? i1 : i0];

  // exact numpy-f32 sequence: (p + 1.0f) * scale - 0.5f  (no contraction)
  float xf0 = (p0.x + 1.0f) * scale - 0.5f;
  float yf0 = (p0.y + 1.0f) * scale - 0.5f;
  float zf0 = (p0.z + 1.0f) * scale - 0.5f;
  float xi0 = floorf(xf0), yi0 = floorf(yf0), zi0 = floorf(zf0);
  float fx0 = xf0 - xi0, fy0 = yf0 - yi0, fz0 = zf0 - zi0;
  int key0 = morton_key(xi0, yi0, zi0, gx, gy, gz, (int)p0.w, depth, cmask);

  float xf1 = (p1.x + 1.0f) * scale - 0.5f;
  float yf1 = (p1.y + 1.0f) * scale - 0.5f;
  float zf1 = (p1.z + 1.0f) * scale - 0.5f;
  float xi1 = floorf(xf1), yi1 = floorf(yf1), zi1 = floorf(zf1);
  float fx1 = xf1 - xi1, fy1 = yf1 - yi1, fz1 = zf1 - zi1;
  int key1 = morton_key(xi1, yi1, zi1, gx, gy, gz, (int)p1.w, depth, cmask);

  // ---- phase B: both presence loads issued back-to-back (8B each) ----
  unsigned long long bits0 = bits8[((unsigned)key0) >> 6];
  unsigned long long bits1 = bits8[((unsigned)key1) >> 6];

  // ---- phase C: presence + row; srt only on hit, keys only on dup ----
  int bit0 = key0 & 63;
  bool present0 = (bits0 >> bit0) & 1ull;
  int pos0 = 0;
  if (present0) {
    unsigned sv = srt[((unsigned)key0) >> 6];
    pos0 = (int)(sv & 0x7FFFFFFFu) +
           (int)__popcll(bits0 & ((1ull << bit0) - 1ull));
    if (sv >> 31) {                 // duplicate-key block: exact scan
      int row = (int)(sv & 0x7FFFFFFFu);
      while (keys[row] < key0) ++row;
      pos0 = row;
    }
  }

  int bit1 = key1 & 63;
  bool present1 = has1 && ((bits1 >> bit1) & 1ull);
  int pos1 = 0;
  if (present1) {
    unsigned sv = srt[((unsigned)key1) >> 6];
    pos1 = (int)(sv & 0x7FFFFFFFu) +
           (int)__popcll(bits1 & ((1ull << bit1) - 1ull));
    if (sv >> 31) {
      int row = (int)(sv & 0x7FFFFFFFu);
      while (keys[row] < key1) ++row;
      pos1 = row;
    }
  }

  // ---- phase D: weights, ballot-driven gather, NT write ----
  int lane = threadIdx.x & 63;
  int base = lane & 56;

  float wx0 = (1.0f - (float)gx) - fx0;
  float wy0 = (1.0f - (float)gy) - fy0;
  float wz0 = (1.0f - (float)gz) - fz0;
  float w0 = present0 ? fabsf((wx0 * wy0) * wz0) : 0.0f;

  float wx1 = (1.0f - (float)gx) - fx1;
  float wy1 = (1.0f - (float)gy) - fy1;
  float wz1 = (1.0f - (float)gz) - fz1;
  float w1 = present1 ? fabsf((wx1 * wy1) * wz1) : 0.0f;

  unsigned long long ball0 = __ballot(w0 != 0.0f);
  unsigned long long ball1 = __ballot(w1 != 0.0f);

  {
    unsigned g8 = (unsigned)((ball0 >> base) & 0xFFull);
    float4 acc = make_float4(0.f, 0.f, 0.f, 0.f);
    float norm = 0.0f;
    while (g8) {
      int q = __ffs(g8) - 1;
      g8 &= g8 - 1;
      float wq = __shfl(w0, base + q, 64);
      int   pq = __shfl(pos0, base + q, 64);
      norm += wq;
      float4 f = reinterpret_cast<const float4*>(data)[pq * 8 + l];
      acc.x += wq * f.x;
      acc.y += wq * f.y;
      acc.z += wq * f.z;
      acc.w += wq * f.w;
    }
    float inv = 1.0f / (norm + 1e-12f);
    f32x4 o = {acc.x * inv, acc.y * inv, acc.z * inv, acc.w * inv};
    __builtin_nontemporal_store(o, reinterpret_cast<f32x4*>(out) + i0 * 8 + l);
  }
  if (has1) {
    unsigned g8 = (unsigned)((ball1 >> base) & 0xFFull);
    float4 acc = make_float4(0.f, 0.f, 0.f, 0.f);
    float norm = 0.0f;
    while (g8) {
      int q = __ffs(g8) - 1;
      g8 &= g8 - 1;
      float wq = __shfl(w1, base + q, 64);
      int   pq = __shfl(pos1, base + q, 64);
      norm += wq;
      float4 f = reinterpret_cast<const float4*>(data)[pq * 8 + l];
      acc.x += wq * f.x;
      acc.y += wq * f.y;
      acc.z += wq * f.z;
      acc.w += wq * f.w;
    }
    float inv = 1.0f / (norm + 1e-12f);
    f32x4 o = {acc.x * inv, acc.y * inv, acc.z * inv, acc.w * inv};
    __builtin_nontemporal_store(o, reinterpret_cast<f32x4*>(out) + i1 * 8 + l);
  }
}

// ---------------------------------------------------------------------------
// Fallback path (small ws or C != 32): bucketed binary search, one thread/point.
// ---------------------------------------------------------------------------
__global__ __launch_bounds__(256) void octi_fill_tab(
    int* __restrict__ tab, int n, int H) {
  int j = blockIdx.x * 256 + threadIdx.x;
  if (j < n) tab[j] = H;
}

__global__ __launch_bounds__(256) void octi_scatter_k(
    const int* __restrict__ keys, int H, const int* __restrict__ depth_ptr,
    int* __restrict__ tab, int kbits) {
  int m = blockIdx.x * 256 + threadIdx.x;
  if (m >= H) return;
  int depth = *depth_ptr;
  int kb = 3 * depth + 2;
  int S = kb > kbits ? kb - kbits : 0;
  int bc = (int)(((unsigned)keys[m]) >> S);
  int bp = (m == 0) ? -1 : (int)(((unsigned)keys[m - 1]) >> S);
  for (int j = bp + 1; j <= bc; ++j) tab[j] = m;
}

__global__ __launch_bounds__(256) void octi_interp_gen(
    const float* __restrict__ data, const float* __restrict__ pts,
    const int* __restrict__ keys, const int* __restrict__ depth_ptr,
    const int* __restrict__ tab, float* __restrict__ out,
    int N, int H, int C, int kbits) {
  int i = blockIdx.x * 256 + threadIdx.x;
  if (i >= N) return;
  int depth = *depth_ptr;
  int kb = 3 * depth + 2;
  int S = kb > kbits ? kb - kbits : 0;
  float scale = (float)(1 << (depth - 1));
  unsigned cmask = (1u << depth) - 1u;
  const float4 p = reinterpret_cast<const float4*>(pts)[i];
  float xf = (p.x + 1.0f) * scale - 0.5f;
  float yf = (p.y + 1.0f) * scale - 0.5f;
  float zf = (p.z + 1.0f) * scale - 0.5f;
  float xi = floorf(xf), yi = floorf(yf), zi = floorf(zf);
  float fx = xf - xi, fy = yf - yi, fz = zf - zi;
  int b = (int)p.w;
  float wv[8]; int pv[8];
  float norm = 0.0f;
  for (int l = 0; l < 8; ++l) {
    int gx = (l >> 2) & 1, gy = (l >> 1) & 1, gz = l & 1;
    int key = morton_key(xi, yi, zi, gx, gy, gz, b, depth, cmask);
    unsigned bkt = ((unsigned)key) >> S;
    int lo = tab ? tab[bkt] : 0;
    int hi = tab ? tab[bkt + 1] : H;
    bool present = false; int posc = 0;
    if (lo < hi) {
      int hi0 = hi;
      while (lo < hi) { int mid = (lo + hi) >> 1; if (keys[mid] < key) lo = mid + 1; else hi = mid; }
      present = (lo < hi0) && (keys[lo] == key);
      posc = lo;
    }
    float wx = (1.0f - (float)gx) - fx;
    float wy = (1.0f - (float)gy) - fy;
    float wz = (1.0f - (float)gz) - fz;
    float w = present ? fabsf((wx * wy) * wz) : 0.0f;
    wv[l] = w; pv[l] = posc; norm += w;
  }
  float dnm = norm + 1e-12f;
  for (int c = 0; c < C; ++c) {
    float acc = 0.0f;
    for (int q = 0; q < 8; ++q)
      if (wv[q] != 0.0f) acc += wv[q] * data[(long long)pv[q] * C + c];
    out[(long long)i * C + c] = acc / dnm;
  }
}

extern "C" void kernel_launch(void* const* d_in, const int* in_sizes, int n_in,
                              void* d_out, int out_size, void* d_ws, size_t ws_size,
                              hipStream_t stream) {
  const float* data = (const float*)d_in[0];
  const float* pts  = (const float*)d_in[1];
  const int*   keys = (const int*)d_in[2];
  const int*   dep  = (const int*)d_in[3];
  float* out = (float*)d_out;

  int H = in_sizes[2];
  int N = in_sizes[1] / 4;
  int C = (H > 0) ? in_sizes[0] / H : 0;

  // workspace layout: bits8 (8 MB) + srt (4 MB) + tab (4 MB + 4)
  size_t off_bits = 0;
  size_t off_srt  = (size_t)NBLKP * 8;
  size_t off_tab  = off_srt + (size_t)NBLKP * 4;
  size_t need = off_tab + ((size_t)NBLKP + 1) * 4;

  if (C == 32 && H > 0 && ws_size >= need) {
    unsigned long long* bits8 = (unsigned long long*)((char*)d_ws + off_bits);
    unsigned* srt = (unsigned*)((char*)d_ws + off_srt);
    int*      tab = (int*)((char*)d_ws + off_tab);

    octi_scatter6<<<(H + 255) / 256, 256, 0, stream>>>(keys, H, tab);
    octi_pack<<<NBLKP / 256, 256, 0, stream>>>(keys, tab, bits8, srt);

    int half = (N + 1) >> 1;
    long long tt = (long long)half * 8;
    octi_interp32<<<(int)((tt + 255) / 256), 256, 0, stream>>>(
        data, pts, keys, dep, bits8, srt, out, N, half);
  } else {
    int kbits = K_BITS;
    int NB1 = (1 << kbits) + 1;
    bool useTab = ws_size >= (size_t)NB1 * sizeof(int);
    int* tab = (int*)d_ws;
    if (useTab) {
      octi_fill_tab<<<(NB1 + 255) / 256, 256, 0, stream>>>(tab, NB1, H);
      octi_scatter_k<<<(H + 255) / 256, 256, 0, stream>>>(keys, H, dep, tab, kbits);
    }
    octi_interp_gen<<<(N + 255) / 256, 256, 0, stream>>>(
        data, pts, keys, dep, useTab ? tab : nullptr, out, N, H, C, kbits);
  }
}

// Round 14
// 64.781 us; speedup vs baseline: 1.1352x; 1.0028x over previous
//
#include <hip/hip_runtime.h>
#include <hip/hip_bf16.h>

// Disable FMA contraction globally: the coordinate transform
// (p+1)*scale-0.5 must round exactly like numpy float32, or floor()
// can flip a cell index and change which octree keys we look up.
#pragma clang fp contract(off)

// Keyspace <= 2^26 (depth=8, B=4). One block per 64 key values.
// Hot structure split by access probability:
//   bits8[b] : u64 presence bits  (8 MB)  -- touched by EVERY corner (97% stop here)
//   srt[b]   : u32 start | dup<<31 (4 MB) -- touched only by hit corners (~3%)
// Both morton-block-indexed (b = key >> 6).
#define NBLKP (1 << 20)
#define K_BITS 18  // fallback bucket bits (1 MB table)

typedef float f32x4 __attribute__((ext_vector_type(4)));

// Morton bit-spread of the low 8 bits of v: bit d -> bit 3d.
// Bit-exact with the reference loop incl. negative / overflowed coords
// (two's complement low bits == the reference's per-bit (v>>d)&1).
__device__ __forceinline__ unsigned morton_spread(unsigned v) {
  v = (v | (v << 16)) & 0x030000FFu;
  v = (v | (v << 8)) & 0x0300F00Fu;
  v = (v | (v << 4)) & 0x030C30C3u;
  v = (v | (v << 2)) & 0x09249249u;
  return v;
}

__device__ __forceinline__ int morton_key(float xi, float yi, float zi,
                                          int gx, int gy, int gz, int b,
                                          int depth, unsigned cmask) {
  unsigned ux = ((unsigned)((int)xi + gx)) & cmask;
  unsigned uy = ((unsigned)((int)yi + gy)) & cmask;
  unsigned uz = ((unsigned)((int)zi + gz)) & cmask;
  return (int)((morton_spread(ux) << 2) | (morton_spread(uy) << 1) |
               morton_spread(uz)) | (b << (3 * depth));
}

// ---------------------------------------------------------------------------
// P1: tab[b] = lower_bound(keys, b<<6), COMPLETE (no prefill needed):
//   thread 0    fills [0, bc_0]
//   thread m    fills (bc_{m-1}, bc_m]
//   thread H-1  additionally fills (bc_{H-1}, NBLKP] with H
// Disjoint ranges -> no races, no atomics. For uniform keys the head/tail
// runs are tiny (~NBLKP/H per thread on average).
// ---------------------------------------------------------------------------
__global__ __launch_bounds__(256) void octi_scatter6(
    const int* __restrict__ keys, int H, int* __restrict__ tab) {
  int m = blockIdx.x * 256 + threadIdx.x;
  if (m >= H) return;
  int bc = (int)(((unsigned)keys[m]) >> 6);
  int bp = (m == 0) ? -1 : (int)(((unsigned)keys[m - 1]) >> 6);
  for (int j = bp + 1; j <= bc; ++j) tab[j] = m;
  if (m == H - 1) {
    for (int j = bc + 1; j <= NBLKP; ++j) tab[j] = H;
  }
}

// ---------------------------------------------------------------------------
// P2: pack per block: bits8[b] = presence bits; srt[b] = start | dup<<31.
// dup=1 iff the block holds a duplicated key (then the main kernel must
// scan keys for the exact searchsorted-left row). Empty blocks: bits=0.
// ---------------------------------------------------------------------------
__global__ __launch_bounds__(256) void octi_pack(
    const int* __restrict__ keys, const int* __restrict__ tab,
    unsigned long long* __restrict__ bits8, unsigned* __restrict__ srt) {
  int b = blockIdx.x * 256 + threadIdx.x;
  if (b >= NBLKP) return;
  int s = tab[b], e = tab[b + 1];
  unsigned long long bits = 0ull;
  for (int m = s; m < e; ++m)
    bits |= 1ull << (((unsigned)keys[m]) & 63u);
  unsigned dup = ((e - s) != __popcll(bits)) ? 1u : 0u;
  bits8[b] = bits;
  srt[b] = (unsigned)s | (dup << 31);
}

// ---------------------------------------------------------------------------
// Main interpolation, C == 32 fast path.  8 lanes per group; each group
// handles TWO independent points (i, i+half).  lane = corner index (lookup)
// and channel-quad (gather/write, float4).  One 8B random load resolves
// presence; hit corners (~3%) read srt (+ rare dup scan of keys).
// NT stores keep the 134 MB out stream from evicting bits8/srt in L2.
// ---------------------------------------------------------------------------
__global__ __launch_bounds__(256) void octi_interp32(
    const float* __restrict__ data, const float* __restrict__ pts,
    const int* __restrict__ keys, const int* __restrict__ depth_ptr,
    const unsigned long long* __restrict__ bits8,
    const unsigned* __restrict__ srt, float* __restrict__ out,
    int N, int half) {
  int t = blockIdx.x * 256 + threadIdx.x;
  int g = t >> 3;
  if (g >= half) return;
  int l = t & 7;
  int i0 = g;
  int i1 = g + half;
  bool has1 = i1 < N;

  int depth = *depth_ptr;
  float scale = (float)(1 << (depth - 1));
  unsigned cmask = (1u << depth) - 1u;
  int gx = (l >> 2) & 1, gy = (l >> 1) & 1, gz = l & 1;

  // ---- phase A: coords + keys for both points ----
  float4 p0 = reinterpret_cast<const float4*>(pts)[i0];
  float4 p1 = reinterpret_cast<const float4*>(pts)[has1 ? i1 : i0];

  // exact numpy-f32 sequence: (p + 1.0f) * scale - 0.5f  (no contraction)
  float xf0 = (p0.x + 1.0f) * scale - 0.5f;
  float yf0 = (p0.y + 1.0f) * scale - 0.5f;
  float zf0 = (p0.z + 1.0f) * scale - 0.5f;
  float xi0 = floorf(xf0), yi0 = floorf(yf0), zi0 = floorf(zf0);
  float fx0 = xf0 - xi0, fy0 = yf0 - yi0, fz0 = zf0 - zi0;
  int key0 = morton_key(xi0, yi0, zi0, gx, gy, gz, (int)p0.w, depth, cmask);

  float xf1 = (p1.x + 1.0f) * scale - 0.5f;
  float yf1 = (p1.y + 1.0f) * scale - 0.5f;
  float zf1 = (p1.z + 1.0f) * scale - 0.5f;
  float xi1 = floorf(xf1), yi1 = floorf(yf1), zi1 = floorf(zf1);
  float fx1 = xf1 - xi1, fy1 = yf1 - yi1, fz1 = zf1 - zi1;
  int key1 = morton_key(xi1, yi1, zi1, gx, gy, gz, (int)p1.w, depth, cmask);

  // ---- phase B: both presence loads issued back-to-back (8B each) ----
  unsigned long long bits0 = bits8[((unsigned)key0) >> 6];
  unsigned long long bits1 = bits8[((unsigned)key1) >> 6];

  // ---- phase C: presence + row; srt only on hit, keys only on dup ----
  int bit0 = key0 & 63;
  bool present0 = (bits0 >> bit0) & 1ull;
  int pos0 = 0;
  if (present0) {
    unsigned sv = srt[((unsigned)key0) >> 6];
    pos0 = (int)(sv & 0x7FFFFFFFu) +
           (int)__popcll(bits0 & ((1ull << bit0) - 1ull));
    if (sv >> 31) {                 // duplicate-key block: exact scan
      int row = (int)(sv & 0x7FFFFFFFu);
      while (keys[row] < key0) ++row;
      pos0 = row;
    }
  }

  int bit1 = key1 & 63;
  bool present1 = has1 && ((bits1 >> bit1) & 1ull);
  int pos1 = 0;
  if (present1) {
    unsigned sv = srt[((unsigned)key1) >> 6];
    pos1 = (int)(sv & 0x7FFFFFFFu) +
           (int)__popcll(bits1 & ((1ull << bit1) - 1ull));
    if (sv >> 31) {
      int row = (int)(sv & 0x7FFFFFFFu);
      while (keys[row] < key1) ++row;
      pos1 = row;
    }
  }

  // ---- phase D: weights, ballot-driven gather, NT write ----
  int lane = threadIdx.x & 63;
  int base = lane & 56;

  float wx0 = (1.0f - (float)gx) - fx0;
  float wy0 = (1.0f - (float)gy) - fy0;
  float wz0 = (1.0f - (float)gz) - fz0;
  float w0 = present0 ? fabsf((wx0 * wy0) * wz0) : 0.0f;

  float wx1 = (1.0f - (float)gx) - fx1;
  float wy1 = (1.0f - (float)gy) - fy1;
  float wz1 = (1.0f - (float)gz) - fz1;
  float w1 = present1 ? fabsf((wx1 * wy1) * wz1) : 0.0f;

  unsigned long long ball0 = __ballot(w0 != 0.0f);
  unsigned long long ball1 = __ballot(w1 != 0.0f);

  {
    unsigned g8 = (unsigned)((ball0 >> base) & 0xFFull);
    float4 acc = make_float4(0.f, 0.f, 0.f, 0.f);
    float norm = 0.0f;
    while (g8) {
      int q = __ffs(g8) - 1;
      g8 &= g8 - 1;
      float wq = __shfl(w0, base + q, 64);
      int   pq = __shfl(pos0, base + q, 64);
      norm += wq;
      float4 f = reinterpret_cast<const float4*>(data)[pq * 8 + l];
      acc.x += wq * f.x;
      acc.y += wq * f.y;
      acc.z += wq * f.z;
      acc.w += wq * f.w;
    }
    float inv = 1.0f / (norm + 1e-12f);
    f32x4 o = {acc.x * inv, acc.y * inv, acc.z * inv, acc.w * inv};
    __builtin_nontemporal_store(o, reinterpret_cast<f32x4*>(out) + i0 * 8 + l);
  }
  if (has1) {
    unsigned g8 = (unsigned)((ball1 >> base) & 0xFFull);
    float4 acc = make_float4(0.f, 0.f, 0.f, 0.f);
    float norm = 0.0f;
    while (g8) {
      int q = __ffs(g8) - 1;
      g8 &= g8 - 1;
      float wq = __shfl(w1, base + q, 64);
      int   pq = __shfl(pos1, base + q, 64);
      norm += wq;
      float4 f = reinterpret_cast<const float4*>(data)[pq * 8 + l];
      acc.x += wq * f.x;
      acc.y += wq * f.y;
      acc.z += wq * f.z;
      acc.w += wq * f.w;
    }
    float inv = 1.0f / (norm + 1e-12f);
    f32x4 o = {acc.x * inv, acc.y * inv, acc.z * inv, acc.w * inv};
    __builtin_nontemporal_store(o, reinterpret_cast<f32x4*>(out) + i1 * 8 + l);
  }
}

// ---------------------------------------------------------------------------
// Fallback path (small ws or C != 32): bucketed binary search, one thread/point.
// ---------------------------------------------------------------------------
__global__ __launch_bounds__(256) void octi_fill_tab(
    int* __restrict__ tab, int n, int H) {
  int j = blockIdx.x * 256 + threadIdx.x;
  if (j < n) tab[j] = H;
}

__global__ __launch_bounds__(256) void octi_scatter_k(
    const int* __restrict__ keys, int H, const int* __restrict__ depth_ptr,
    int* __restrict__ tab, int kbits) {
  int m = blockIdx.x * 256 + threadIdx.x;
  if (m >= H) return;
  int depth = *depth_ptr;
  int kb = 3 * depth + 2;
  int S = kb > kbits ? kb - kbits : 0;
  int bc = (int)(((unsigned)keys[m]) >> S);
  int bp = (m == 0) ? -1 : (int)(((unsigned)keys[m - 1]) >> S);
  for (int j = bp + 1; j <= bc; ++j) tab[j] = m;
}

__global__ __launch_bounds__(256) void octi_interp_gen(
    const float* __restrict__ data, const float* __restrict__ pts,
    const int* __restrict__ keys, const int* __restrict__ depth_ptr,
    const int* __restrict__ tab, float* __restrict__ out,
    int N, int H, int C, int kbits) {
  int i = blockIdx.x * 256 + threadIdx.x;
  if (i >= N) return;
  int depth = *depth_ptr;
  int kb = 3 * depth + 2;
  int S = kb > kbits ? kb - kbits : 0;
  float scale = (float)(1 << (depth - 1));
  unsigned cmask = (1u << depth) - 1u;
  const float4 p = reinterpret_cast<const float4*>(pts)[i];
  float xf = (p.x + 1.0f) * scale - 0.5f;
  float yf = (p.y + 1.0f) * scale - 0.5f;
  float zf = (p.z + 1.0f) * scale - 0.5f;
  float xi = floorf(xf), yi = floorf(yf), zi = floorf(zf);
  float fx = xf - xi, fy = yf - yi, fz = zf - zi;
  int b = (int)p.w;
  float wv[8]; int pv[8];
  float norm = 0.0f;
  for (int l = 0; l < 8; ++l) {
    int gx = (l >> 2) & 1, gy = (l >> 1) & 1, gz = l & 1;
    int key = morton_key(xi, yi, zi, gx, gy, gz, b, depth, cmask);
    unsigned bkt = ((unsigned)key) >> S;
    int lo = tab ? tab[bkt] : 0;
    int hi = tab ? tab[bkt + 1] : H;
    bool present = false; int posc = 0;
    if (lo < hi) {
      int hi0 = hi;
      while (lo < hi) { int mid = (lo + hi) >> 1; if (keys[mid] < key) lo = mid + 1; else hi = mid; }
      present = (lo < hi0) && (keys[lo] == key);
      posc = lo;
    }
    float wx = (1.0f - (float)gx) - fx;
    float wy = (1.0f - (float)gy) - fy;
    float wz = (1.0f - (float)gz) - fz;
    float w = present ? fabsf((wx * wy) * wz) : 0.0f;
    wv[l] = w; pv[l] = posc; norm += w;
  }
  float dnm = norm + 1e-12f;
  for (int c = 0; c < C; ++c) {
    float acc = 0.0f;
    for (int q = 0; q < 8; ++q)
      if (wv[q] != 0.0f) acc += wv[q] * data[(long long)pv[q] * C + c];
    out[(long long)i * C + c] = acc / dnm;
  }
}

extern "C" void kernel_launch(void* const* d_in, const int* in_sizes, int n_in,
                              void* d_out, int out_size, void* d_ws, size_t ws_size,
                              hipStream_t stream) {
  const float* data = (const float*)d_in[0];
  const float* pts  = (const float*)d_in[1];
  const int*   keys = (const int*)d_in[2];
  const int*   dep  = (const int*)d_in[3];
  float* out = (float*)d_out;

  int H = in_sizes[2];
  int N = in_sizes[1] / 4;
  int C = (H > 0) ? in_sizes[0] / H : 0;

  // workspace layout: bits8 (8 MB) + srt (4 MB) + tab (4 MB + 4)
  size_t off_bits = 0;
  size_t off_srt  = (size_t)NBLKP * 8;
  size_t off_tab  = off_srt + (size_t)NBLKP * 4;
  size_t need = off_tab + ((size_t)NBLKP + 1) * 4;

  if (C == 32 && H > 0 && ws_size >= need) {
    unsigned long long* bits8 = (unsigned long long*)((char*)d_ws + off_bits);
    unsigned* srt = (unsigned*)((char*)d_ws + off_srt);
    int*      tab = (int*)((char*)d_ws + off_tab);

    octi_scatter6<<<(H + 255) / 256, 256, 0, stream>>>(keys, H, tab);
    octi_pack<<<NBLKP / 256, 256, 0, stream>>>(keys, tab, bits8, srt);

    int half = (N + 1) >> 1;
    long long tt = (long long)half * 8;
    octi_interp32<<<(int)((tt + 255) / 256), 256, 0, stream>>>(
        data, pts, keys, dep, bits8, srt, out, N, half);
  } else {
    int kbits = K_BITS;
    int NB1 = (1 << kbits) + 1;
    bool useTab = ws_size >= (size_t)NB1 * sizeof(int);
    int* tab = (int*)d_ws;
    if (useTab) {
      octi_fill_tab<<<(NB1 + 255) / 256, 256, 0, stream>>>(tab, NB1, H);
      octi_scatter_k<<<(H + 255) / 256, 256, 0, stream>>>(keys, H, dep, tab, kbits);
    }
    octi_interp_gen<<<(N + 255) / 256, 256, 0, stream>>>(
        data, pts, keys, dep, useTab ? tab : nullptr, out, N, H, C, kbits);
  }
}